// Round 14
// baseline (5801.399 us; speedup 1.0000x reference)
//
#include <hip/hip_runtime.h>
#include <hip/hip_bf16.h>

#define NV 4000
#define NL 8000
#define NC 16800
#define NE 50400
#define FM 256
#define ROUNDS 32

typedef short s16x8 __attribute__((ext_vector_type(8)));
typedef __bf16 b16x8 __attribute__((ext_vector_type(8)));
typedef float f32x4 __attribute__((ext_vector_type(4)));
union V8 { s16x8 s; b16x8 b; ushort u[8]; };

using gaddr_t = const void __attribute__((address_space(1)))*;
using laddr_t = void __attribute__((address_space(3)))*;

__device__ __forceinline__ float b2f(ushort u) {
    union { uint i; float f; } v; v.i = ((uint)u) << 16; return v.f;
}
__device__ __forceinline__ ushort f2b(float f) {
    __hip_bfloat16 h = __float2bfloat16(f);
    return *(ushort*)&h;
}

// ---------------- utility ----------------
__global__ void zero_kernel(float* __restrict__ p, int n) {
    int i = blockIdx.x * blockDim.x + threadIdx.x;
    if (i < n) p[i] = 0.0f;
}
__global__ void f2b_kernel(const float* __restrict__ src, ushort* __restrict__ dst, int n) {
    int i = blockIdx.x * blockDim.x + threadIdx.x;
    if (i < n) dst[i] = f2b(src[i]);
}
// six 256x256 W [K,N] fp32 -> [N,256] bf16 transposes in one dispatch
__global__ void transpose_w6_kernel(
    const float* __restrict__ s0, const float* __restrict__ s1, const float* __restrict__ s2,
    const float* __restrict__ s3, const float* __restrict__ s4, const float* __restrict__ s5,
    ushort* __restrict__ d0, ushort* __restrict__ d1, ushort* __restrict__ d2,
    ushort* __restrict__ d3, ushort* __restrict__ d4, ushort* __restrict__ d5)
{
    const float* srcs[6] = {s0, s1, s2, s3, s4, s5};
    ushort* dsts[6] = {d0, d1, d2, d3, d4, d5};
    const float* in = srcs[blockIdx.y];
    ushort* out = dsts[blockIdx.y];
    int idx = blockIdx.x * blockDim.x + threadIdx.x;
    int n = idx >> 8, k = idx & 255;
    out[n * 256 + k] = f2b(in[k * 256 + n]);
}
// W [K,N] fp32 -> out [N', ldo] bf16 at k-offset koff; perm: row = (n&255)*4 + (n>>8)
__global__ void transpose_w_kernel(const float* __restrict__ in, ushort* __restrict__ out,
                                   int K, int N, int ldo, int koff, int perm) {
    int idx = blockIdx.x * blockDim.x + threadIdx.x;
    if (idx >= K * N) return;
    int n = idx / K, k = idx - n * K;
    int row = perm ? ((n & 255) * 4 + (n >> 8)) : n;
    out[(size_t)row * ldo + koff + k] = f2b(in[(size_t)k * N + n]);
}
__global__ void permute_bias_kernel(const float* __restrict__ b, float* __restrict__ bp) {
    int n = blockIdx.x * blockDim.x + threadIdx.x;
    if (n < 1024) bp[(n & 255) * 4 + (n >> 8)] = b[n];
}

// ---------------- combined state init ----------------
__global__ void init_all_kernel(const float* __restrict__ Li, const float* __restrict__ Ci,
                                ushort* __restrict__ lh, float* __restrict__ lc32,
                                ushort* __restrict__ ch, float* __restrict__ cc32) {
    int idx = blockIdx.x * blockDim.x + threadIdx.x;
    if (idx < NL * FM) { lh[idx] = f2b(Li[idx & 255] * (1.0f / 16.0f)); lc32[idx] = 0.0f; }
    if (idx < NC * FM) { ch[idx] = f2b(Ci[idx & 255] * (1.0f / 16.0f)); cc32[idx] = 0.0f; }
}
__global__ void fill_hist_kernel(float* __restrict__ hist, const float* __restrict__ b2,
                                 float* __restrict__ loss_arr) {
    int i = blockIdx.x * blockDim.x + threadIdx.x;
    if (i < ROUNDS * NV) hist[i] = b2[0];
    if (i < ROUNDS) loss_arr[i] = 0.0f;
}

// ---------------- CSR build ----------------
__global__ void csr_count_kernel(const int* __restrict__ lits, int* __restrict__ deg) {
    int e = blockIdx.x * blockDim.x + threadIdx.x;
    if (e >= NE) return;
    int l = lits[e];
    int v = (l > 0 ? l : -l) - 1;
    int li = (l > 0) ? v : NV + v;
    atomicAdd(&deg[li], 1);
}
__global__ __launch_bounds__(1024) void csr_scan_kernel(const int* __restrict__ deg,
                                                        int* __restrict__ rowptr,
                                                        int* __restrict__ nxt) {
    __shared__ int ls[1024];
    int t = threadIdx.x;
    int base = t * 8;
    int local[8];
    int s = 0;
    #pragma unroll
    for (int i = 0; i < 8; ++i) {
        int idx = base + i;
        int d = (idx < NL) ? deg[idx] : 0;
        local[i] = s;
        s += d;
    }
    ls[t] = s;
    __syncthreads();
    for (int st = 1; st < 1024; st <<= 1) {
        int v = (t >= st) ? ls[t - st] : 0;
        __syncthreads();
        ls[t] += v;
        __syncthreads();
    }
    int prefix = (t == 0) ? 0 : ls[t - 1];
    #pragma unroll
    for (int i = 0; i < 8; ++i) {
        int idx = base + i;
        if (idx < NL) { int v = prefix + local[i]; rowptr[idx] = v; nxt[idx] = v; }
    }
    if (t == 1023) rowptr[NL] = ls[1023];
}
__global__ void csr_fill_kernel(const int* __restrict__ lits, int* __restrict__ nxt,
                                int* __restrict__ ecl) {
    int e = blockIdx.x * blockDim.x + threadIdx.x;
    if (e >= NE) return;
    int l = lits[e];
    int v = (l > 0 ? l : -l) - 1;
    int li = (l > 0) ? v : NV + v;
    int pos = atomicAdd(&nxt[li], 1);
    ecl[pos] = e / 3;
}

#define BKT 64

// =========== Fused 3-layer MLP, W double-buffered (1 block/CU kernel) ===========
#define MLPR 32
__global__ __launch_bounds__(256) void mlp3_kernel(
    const ushort* __restrict__ A,
    const ushort* __restrict__ W0t, const float* __restrict__ b0,
    const ushort* __restrict__ W1t, const float* __restrict__ b1,
    const ushort* __restrict__ W2t, const float* __restrict__ b2,
    ushort* __restrict__ out, int M)
{
    __shared__ __align__(16) ushort As[2][MLPR * BKT];
    __shared__ __align__(16) ushort Wl[2][256 * BKT];
    __shared__ __align__(16) ushort Ab[MLPR * 264];
    const int tid = threadIdx.x;
    const int lane = tid & 63, wid = tid >> 6;
    const int rowBase = blockIdx.x * MLPR;
    const int lr = lane >> 3, ql = (lane & 7) ^ lr;
    const int cl16 = lane & 15, kg = lane >> 4;

    const ushort* Wt[3] = {W0t, W1t, W2t};
    const float*  bs[3] = {b0, b1, b2};

    auto stage = [&](int t, int p) {
        int layer = t >> 2, kt = t & 3;
        #pragma unroll
        for (int q = 0; q < 8; ++q) {
            int row = wid * 64 + q * 8 + lr;
            __builtin_amdgcn_global_load_lds(
                (gaddr_t)(Wt[layer] + (size_t)row * 256 + kt * 64 + ql * 8),
                (laddr_t)&Wl[p][(wid * 64 + q * 8) * BKT + lane * 8], 16, 0, 0);
        }
        if (t < 4) {
            int row = rowBase + wid * 8 + lr;
            if (row > M - 1) row = M - 1;
            __builtin_amdgcn_global_load_lds(
                (gaddr_t)(A + (size_t)row * 256 + kt * 64 + ql * 8),
                (laddr_t)&As[p][wid * 512 + lane * 8], 16, 0, 0);
        }
    };

    f32x4 acc[2][4];
    #pragma unroll
    for (int i = 0; i < 2; ++i)
        #pragma unroll
        for (int j = 0; j < 4; ++j) acc[i][j] = (f32x4){0.f, 0.f, 0.f, 0.f};

    stage(0, 0);
    for (int t = 0; t < 12; ++t) {
        const int layer = t >> 2, kt = t & 3, p = t & 1;
        __syncthreads();                     // drains DMA(t); publishes prior Ab writes
        if (t + 1 < 12) stage(t + 1, (t + 1) & 1);
        #pragma unroll
        for (int s = 0; s < 2; ++s) {
            int kq8 = s * 4 + kg;
            V8 af[2], bf[4];
            #pragma unroll
            for (int i = 0; i < 2; ++i) {
                int m = i * 16 + cl16;
                if (layer == 0)
                    af[i].s = *(const s16x8*)&As[p][m * BKT + ((kq8 ^ (m & 7)) * 8)];
                else
                    af[i].s = *(const s16x8*)&Ab[m * 264 + kt * 64 + kq8 * 8];
            }
            #pragma unroll
            for (int j = 0; j < 4; ++j) {
                int n = wid * 64 + j * 16 + cl16;
                bf[j].s = *(const s16x8*)&Wl[p][n * BKT + ((kq8 ^ (n & 7)) * 8)];
            }
            #pragma unroll
            for (int i = 0; i < 2; ++i)
                #pragma unroll
                for (int j = 0; j < 4; ++j)
                    acc[i][j] = __builtin_amdgcn_mfma_f32_16x16x32_bf16(
                        af[i].b, bf[j].b, acc[i][j], 0, 0, 0);
        }
        if (kt == 3) {
            if (layer == 1) __syncthreads();   // all Ab reads done before overwrite
            const int rq = (lane >> 4) * 4;
            #pragma unroll
            for (int i = 0; i < 2; ++i)
                #pragma unroll
                for (int r = 0; r < 4; ++r) {
                    int row = i * 16 + rq + r;
                    #pragma unroll
                    for (int j = 0; j < 4; ++j) {
                        int col = wid * 64 + j * 16 + cl16;
                        float v = acc[i][j][r] + bs[layer][col];
                        if (layer < 2) {
                            Ab[row * 264 + col] = f2b(fmaxf(v, 0.0f));
                        } else {
                            int grow = rowBase + row;
                            if (grow < M) out[(size_t)grow * 256 + col] = f2b(v);
                        }
                    }
                }
            #pragma unroll
            for (int i = 0; i < 2; ++i)
                #pragma unroll
                for (int j = 0; j < 4; ++j) acc[i][j] = (f32x4){0.f, 0.f, 0.f, 0.f};
        }
    }
}

// =========== MFMA bf16 GEMM 128x64 tile, double-buffered staging ===========
__global__ __launch_bounds__(256) void gemm16_n64_kernel(
    const ushort* __restrict__ A0, int K0,
    const ushort* __restrict__ A1, int K1,
    const ushort* __restrict__ Bt, const float* __restrict__ bias,
    ushort* __restrict__ C, int M, int N, int relu)
{
    __shared__ __align__(16) ushort Al[2][128 * BKT];
    __shared__ __align__(16) ushort Bl[2][64 * BKT];
    const int Ktot = K0 + K1;
    const int nk = Ktot / BKT;
    const int tid = threadIdx.x;
    const int rowBase = blockIdx.y * 128, colBase = blockIdx.x * 64;
    const int lane = tid & 63, wid = tid >> 6;
    const int wm = (wid & 1) * 64, wn = (wid >> 1) * 32;
    const int lr = lane >> 3, ql = (lane & 7) ^ lr;

    auto stage = [&](int kc, int p) {
        int k0 = kc * BKT;
        const ushort* As; int ks, lda;
        if (k0 < K0) { As = A0; ks = k0; lda = K0; }
        else         { As = A1; ks = k0 - K0; lda = K1; }
        #pragma unroll
        for (int t = 0; t < 4; ++t) {
            int rloc = (wid * 4 + t) * 8 + lr;
            int ga = rowBase + rloc; if (ga > M - 1) ga = M - 1;
            __builtin_amdgcn_global_load_lds((gaddr_t)(As + (size_t)ga * lda + ks + ql * 8),
                                             (laddr_t)&Al[p][(wid * 4 + t) * 512], 16, 0, 0);
        }
        #pragma unroll
        for (int t = 0; t < 2; ++t) {
            int rloc = (wid * 2 + t) * 8 + lr;
            __builtin_amdgcn_global_load_lds((gaddr_t)(Bt + (size_t)(colBase + rloc) * Ktot + k0 + ql * 8),
                                             (laddr_t)&Bl[p][(wid * 2 + t) * 512], 16, 0, 0);
        }
    };

    f32x4 acc[4][2];
    #pragma unroll
    for (int i = 0; i < 4; ++i)
        #pragma unroll
        for (int j = 0; j < 2; ++j) acc[i][j] = (f32x4){0.f, 0.f, 0.f, 0.f};

    stage(0, 0);
    for (int kc = 0; kc < nk; ++kc) {
        __syncthreads();
        if (kc + 1 < nk) stage(kc + 1, (kc + 1) & 1);
        const int p = kc & 1;
        const int cl = lane & 15, kg = lane >> 4;
        #pragma unroll
        for (int s = 0; s < 2; ++s) {
            V8 af[4], bf[2];
            #pragma unroll
            for (int i = 0; i < 4; ++i) {
                int m = wm + i * 16 + cl;
                af[i].s = *(const s16x8*)&Al[p][m * BKT + (((s * 4 + kg) ^ (m & 7)) * 8)];
            }
            #pragma unroll
            for (int j = 0; j < 2; ++j) {
                int n = wn + j * 16 + cl;
                bf[j].s = *(const s16x8*)&Bl[p][n * BKT + (((s * 4 + kg) ^ (n & 7)) * 8)];
            }
            #pragma unroll
            for (int i = 0; i < 4; ++i)
                #pragma unroll
                for (int j = 0; j < 2; ++j)
                    acc[i][j] = __builtin_amdgcn_mfma_f32_16x16x32_bf16(af[i].b, bf[j].b,
                                                                        acc[i][j], 0, 0, 0);
        }
    }
    const int rq = (lane >> 4) * 4, cl = lane & 15;
    #pragma unroll
    for (int i = 0; i < 4; ++i)
        #pragma unroll
        for (int r = 0; r < 4; ++r) {
            int grow = rowBase + wm + i * 16 + rq + r;
            if (grow >= M) continue;
            #pragma unroll
            for (int j = 0; j < 2; ++j) {
                int gcol = colBase + wn + j * 16 + cl;
                float v = acc[i][j][r] + bias[gcol];
                if (relu) v = fmaxf(v, 0.0f);
                C[(size_t)grow * N + gcol] = f2b(v);
            }
        }
}

// =========== vote layer-1 GEMM + GEMV fused, double-buffered staging ===========
__global__ __launch_bounds__(256) void gemm16_vote_kernel(
    const ushort* __restrict__ A0,              // v0 [M,512]
    const ushort* __restrict__ Bt,              // VW1t [512,512]
    const float* __restrict__ bias,             // Vb1
    const ushort* __restrict__ w2,              // vw2 bf16 [512]
    float* __restrict__ logits, int M)          // pre-filled with b2
{
    __shared__ __align__(16) ushort Al[2][128 * BKT];
    __shared__ __align__(16) ushort Bl[2][64 * BKT];
    const int Ktot = 512;
    const int nk = Ktot / BKT;
    const int tid = threadIdx.x;
    const int rowBase = blockIdx.y * 128, colBase = blockIdx.x * 64;
    const int lane = tid & 63, wid = tid >> 6;
    const int wm = (wid & 1) * 64, wn = (wid >> 1) * 32;
    const int lr = lane >> 3, ql = (lane & 7) ^ lr;

    auto stage = [&](int kc, int p) {
        int k0 = kc * BKT;
        #pragma unroll
        for (int t = 0; t < 4; ++t) {
            int rloc = (wid * 4 + t) * 8 + lr;
            int ga = rowBase + rloc; if (ga > M - 1) ga = M - 1;
            __builtin_amdgcn_global_load_lds((gaddr_t)(A0 + (size_t)ga * Ktot + k0 + ql * 8),
                                             (laddr_t)&Al[p][(wid * 4 + t) * 512], 16, 0, 0);
        }
        #pragma unroll
        for (int t = 0; t < 2; ++t) {
            int rloc = (wid * 2 + t) * 8 + lr;
            __builtin_amdgcn_global_load_lds((gaddr_t)(Bt + (size_t)(colBase + rloc) * Ktot + k0 + ql * 8),
                                             (laddr_t)&Bl[p][(wid * 2 + t) * 512], 16, 0, 0);
        }
    };

    f32x4 acc[4][2];
    #pragma unroll
    for (int i = 0; i < 4; ++i)
        #pragma unroll
        for (int j = 0; j < 2; ++j) acc[i][j] = (f32x4){0.f, 0.f, 0.f, 0.f};

    stage(0, 0);
    for (int kc = 0; kc < nk; ++kc) {
        __syncthreads();
        if (kc + 1 < nk) stage(kc + 1, (kc + 1) & 1);
        const int p = kc & 1;
        const int cl = lane & 15, kg = lane >> 4;
        #pragma unroll
        for (int s = 0; s < 2; ++s) {
            V8 af[4], bf[2];
            #pragma unroll
            for (int i = 0; i < 4; ++i) {
                int m = wm + i * 16 + cl;
                af[i].s = *(const s16x8*)&Al[p][m * BKT + (((s * 4 + kg) ^ (m & 7)) * 8)];
            }
            #pragma unroll
            for (int j = 0; j < 2; ++j) {
                int n = wn + j * 16 + cl;
                bf[j].s = *(const s16x8*)&Bl[p][n * BKT + (((s * 4 + kg) ^ (n & 7)) * 8)];
            }
            #pragma unroll
            for (int i = 0; i < 4; ++i)
                #pragma unroll
                for (int j = 0; j < 2; ++j)
                    acc[i][j] = __builtin_amdgcn_mfma_f32_16x16x32_bf16(af[i].b, bf[j].b,
                                                                        acc[i][j], 0, 0, 0);
        }
    }
    const int rq = (lane >> 4) * 4, cl = lane & 15;
    #pragma unroll
    for (int i = 0; i < 4; ++i)
        #pragma unroll
        for (int r = 0; r < 4; ++r) {
            int grow = rowBase + wm + i * 16 + rq + r;
            float s = 0.0f;
            #pragma unroll
            for (int j = 0; j < 2; ++j) {
                int gcol = colBase + wn + j * 16 + cl;
                float h1 = b2f(f2b(fmaxf(acc[i][j][r] + bias[gcol], 0.0f)));
                s += h1 * b2f(w2[gcol]);
            }
            s += __shfl_xor(s, 1);
            s += __shfl_xor(s, 2);
            s += __shfl_xor(s, 4);
            s += __shfl_xor(s, 8);
            if (cl == 0 && grow < M) atomicAdd(&logits[grow], s);
        }
}

// =========== Fused z-GEMM + LSTM (N=1024, gate-interleaved weights) ===========
__global__ __launch_bounds__(256) void gemm_lstm_kernel(
    const ushort* __restrict__ A0, int K0,
    const ushort* __restrict__ A1, int K1,
    const ushort* __restrict__ A2, int K2,
    int flip1,
    const ushort* __restrict__ Bt, const float* __restrict__ biasP,
    float* __restrict__ c32, ushort* __restrict__ h_out, int M)
{
    __shared__ __align__(16) ushort smem[2 * 128 * BKT];
    ushort* Al = smem;
    ushort* Bl = smem + 128 * BKT;
    const int Ktot = K0 + K1 + K2;
    const int tid = threadIdx.x;
    const int rowBase = blockIdx.y * 128, colBase = blockIdx.x * 128;
    const int lane = tid & 63, wid = tid >> 6;
    const int wm = (wid >> 1) * 64, wn = (wid & 1) * 64;
    const int lr = lane >> 3, ql = (lane & 7) ^ lr;

    f32x4 acc[4][4];
    #pragma unroll
    for (int i = 0; i < 4; ++i)
        #pragma unroll
        for (int j = 0; j < 4; ++j) acc[i][j] = (f32x4){0.f, 0.f, 0.f, 0.f};

    for (int k0 = 0; k0 < Ktot; k0 += BKT) {
        const ushort* As; int ks, lda, flip;
        if (k0 < K0)           { As = A0; ks = k0;           lda = K0; flip = 0; }
        else if (k0 < K0 + K1) { As = A1; ks = k0 - K0;      lda = K1; flip = flip1; }
        else                   { As = A2; ks = k0 - K0 - K1; lda = K2; flip = 0; }
        __syncthreads();
        #pragma unroll
        for (int t = 0; t < 4; ++t) {
            int rloc = (wid * 4 + t) * 8 + lr;
            int ga = rowBase + rloc; if (ga > M - 1) ga = M - 1;
            if (flip) ga = (ga < NV) ? ga + NV : ga - NV;
            __builtin_amdgcn_global_load_lds((gaddr_t)(As + (size_t)ga * lda + ks + ql * 8),
                                             (laddr_t)&Al[(wid * 4 + t) * 512], 16, 0, 0);
            __builtin_amdgcn_global_load_lds((gaddr_t)(Bt + (size_t)(colBase + rloc) * Ktot + k0 + ql * 8),
                                             (laddr_t)&Bl[(wid * 4 + t) * 512], 16, 0, 0);
        }
        __syncthreads();
        const int cl = lane & 15, kg = lane >> 4;
        #pragma unroll
        for (int s = 0; s < 2; ++s) {
            V8 af[4], bf[4];
            #pragma unroll
            for (int i = 0; i < 4; ++i) {
                int m = wm + i * 16 + cl;
                af[i].s = *(const s16x8*)&Al[m * BKT + (((s * 4 + kg) ^ (m & 7)) * 8)];
            }
            #pragma unroll
            for (int j = 0; j < 4; ++j) {
                int n = wn + j * 16 + cl;
                bf[j].s = *(const s16x8*)&Bl[n * BKT + (((s * 4 + kg) ^ (n & 7)) * 8)];
            }
            #pragma unroll
            for (int i = 0; i < 4; ++i)
                #pragma unroll
                for (int j = 0; j < 4; ++j)
                    acc[i][j] = __builtin_amdgcn_mfma_f32_16x16x32_bf16(af[i].b, bf[j].b,
                                                                        acc[i][j], 0, 0, 0);
        }
    }
    __syncthreads();
    {
        const int rq = (lane >> 4) * 4, cl = lane & 15;
        #pragma unroll
        for (int i = 0; i < 4; ++i)
            #pragma unroll
            for (int r = 0; r < 4; ++r) {
                int rl = wm + i * 16 + rq + r;
                #pragma unroll
                for (int j = 0; j < 4; ++j) {
                    int clc = wn + j * 16 + cl;
                    smem[rl * 128 + clc] = f2b(acc[i][j][r] + biasP[colBase + clc]);
                }
            }
    }
    __syncthreads();
    const int fl = tid & 31, rg = tid >> 5;
    const int fglob = (colBase >> 2) + fl;
    #pragma unroll
    for (int k = 0; k < 16; ++k) {
        int rl = rg + 8 * k;
        int grow = rowBase + rl;
        if (grow >= M) continue;
        ushort4 g4 = *(const ushort4*)&smem[rl * 128 + fl * 4];
        float zi = b2f(g4.x), zf = b2f(g4.y), zg = b2f(g4.z), zo = b2f(g4.w);
        size_t ci = (size_t)grow * FM + fglob;
        float cold = c32[ci];
        float si = 1.0f / (1.0f + __expf(-zi));
        float sf = 1.0f / (1.0f + __expf(-zf));
        float so = 1.0f / (1.0f + __expf(-zo));
        float cn = sf * cold + si * tanhf(zg);
        float hn = so * tanhf(cn);
        c32[ci] = cn;
        h_out[ci] = f2b(hn);
    }
}

// ---------------- gather (vectorized x8) ----------------
__global__ void gather_lc8_kernel(const ushort* __restrict__ pre, const int* __restrict__ lits,
                                  ushort* __restrict__ out) {
    int idx = blockIdx.x * blockDim.x + threadIdx.x;
    if (idx >= NC * 32) return;
    int c = idx >> 5, f8 = (idx & 31) * 8;
    const int* cl = lits + c * 3;
    float s[8] = {};
    #pragma unroll
    for (int k = 0; k < 3; ++k) {
        int l = cl[k];
        int v = (l > 0 ? l : -l) - 1;
        int li = (l > 0) ? v : NV + v;
        V8 x; x.s = *(const s16x8*)&pre[(size_t)li * FM + f8];
        #pragma unroll
        for (int e = 0; e < 8; ++e) s[e] += b2f(x.u[e]);
    }
    V8 o;
    #pragma unroll
    for (int e = 0; e < 8; ++e) o.u[e] = f2b(s[e]);
    *(s16x8*)&out[(size_t)c * FM + f8] = o.s;
}

__global__ void gather_cl8_kernel(const ushort* __restrict__ pre, const int* __restrict__ rowptr,
                                  const int* __restrict__ ecl, ushort* __restrict__ out) {
    int idx = blockIdx.x * blockDim.x + threadIdx.x;
    if (idx >= NL * 32) return;
    int li = idx >> 5, f8 = (idx & 31) * 8;
    int j0 = rowptr[li], j1 = rowptr[li + 1];
    float s[8] = {};
    for (int j = j0; j < j1; ++j) {
        V8 x; x.s = *(const s16x8*)&pre[(size_t)ecl[j] * FM + f8];
        #pragma unroll
        for (int e = 0; e < 8; ++e) s[e] += b2f(x.u[e]);
    }
    V8 o;
    #pragma unroll
    for (int e = 0; e < 8; ++e) o.u[e] = f2b(s[e]);
    *(s16x8*)&out[(size_t)li * FM + f8] = o.s;
}

// ---------------- batched clause loss over all rounds ----------------
__global__ __launch_bounds__(256) void loss_all_kernel(
    const float* __restrict__ logits_hist, const int* __restrict__ lits,
    float* __restrict__ loss_arr)
{
    __shared__ float sm[256];
    const int r = blockIdx.y;
    const float* logits = logits_hist + (size_t)r * NV;
    int c = blockIdx.x * 256 + threadIdx.x;
    float t2 = 0.0f;
    if (c < NC) {
        const int* cl = lits + c * 3;
        float s = 0.0f;
        #pragma unroll
        for (int k = 0; k < 3; ++k) {
            int l = cl[k];
            int v = (l > 0 ? l : -l) - 1;
            float sg = (l > 0) ? 1.0f : -1.0f;
            float val = logits[v] * sg;
            s += fmaxf(val, 0.0f) + log1pf(__expf(-fabsf(val)));
        }
        float cv = __expf(-s);
        float t = -logf(1.0f - cv + 1e-8f);
        t2 = t * t;
    }
    sm[threadIdx.x] = t2;
    __syncthreads();
    for (int st = 128; st > 0; st >>= 1) {
        if (threadIdx.x < st) sm[threadIdx.x] += sm[threadIdx.x + st];
        __syncthreads();
    }
    if (threadIdx.x == 0) atomicAdd(&loss_arr[r], sm[0]);
}

// ---------------- final: copy last-round logits + mean loss ----------------
__global__ void final_out_kernel(const float* __restrict__ logits_hist,
                                 const float* __restrict__ loss_arr,
                                 float* __restrict__ out) {
    int i = blockIdx.x * blockDim.x + threadIdx.x;
    if (i < NV) out[i] = logits_hist[(size_t)(ROUNDS - 1) * NV + i];
    if (i == NV) {
        float s = 0.0f;
        for (int r = 0; r < ROUNDS; ++r) s += loss_arr[r];
        out[NV] = s * (1.0f / (float)ROUNDS);
    }
}

extern "C" void kernel_launch(void* const* d_in, const int* in_sizes, int n_in,
                              void* d_out, int out_size, void* d_ws, size_t ws_size,
                              hipStream_t stream) {
    const int* lits = (const int*)d_in[0];
    float* out = (float*)d_out;

    const float* Li   = (const float*)d_in[2];
    const float* Ci   = (const float*)d_in[3];
    const float* LCW0 = (const float*)d_in[4];
    const float* LCb0 = (const float*)d_in[5];
    const float* LCW1 = (const float*)d_in[6];
    const float* LCb1 = (const float*)d_in[7];
    const float* LCW2 = (const float*)d_in[8];
    const float* LCb2 = (const float*)d_in[9];
    const float* CLW0 = (const float*)d_in[10];
    const float* CLb0 = (const float*)d_in[11];
    const float* CLW1 = (const float*)d_in[12];
    const float* CLb1 = (const float*)d_in[13];
    const float* CLW2 = (const float*)d_in[14];
    const float* CLb2 = (const float*)d_in[15];
    const float* CWx  = (const float*)d_in[16];
    const float* CWh  = (const float*)d_in[17];
    const float* Cb   = (const float*)d_in[18];
    const float* LWx  = (const float*)d_in[19];
    const float* LWh  = (const float*)d_in[20];
    const float* Lb   = (const float*)d_in[21];
    const float* VW0  = (const float*)d_in[22];
    const float* Vb0  = (const float*)d_in[23];
    const float* VW1  = (const float*)d_in[24];
    const float* Vb1  = (const float*)d_in[25];
    const float* VW2  = (const float*)d_in[26];
    const float* Vb2  = (const float*)d_in[27];
    (void)in_sizes; (void)n_in; (void)out_size; (void)ws_size;

    // ---- ws layout ----
    char* base = (char*)d_ws;
    size_t off = 0;
    auto allocB = [&](size_t bytes) {
        void* p = base + off;
        off += (bytes + 15) & ~(size_t)15;
        return p;
    };
    float*  loss_arr    = (float*)allocB(ROUNDS * 4);
    float*  logits_hist = (float*)allocB((size_t)ROUNDS * NV * 4);
    float*  lc32        = (float*)allocB((size_t)NL * FM * 4);
    float*  cc32        = (float*)allocB((size_t)NC * FM * 4);
    float*  Cb_p        = (float*)allocB(1024 * 4);
    float*  Lb_p        = (float*)allocB(1024 * 4);
    int*    deg         = (int*)allocB(NL * 4);
    int*    rowptr      = (int*)allocB((NL + 1) * 4);
    int*    nxt         = (int*)allocB(NL * 4);
    int*    ecl         = (int*)allocB(NE * 4);
    ushort* LC0t = (ushort*)allocB((size_t)256 * 256 * 2);
    ushort* LC1t = (ushort*)allocB((size_t)256 * 256 * 2);
    ushort* LC2t = (ushort*)allocB((size_t)256 * 256 * 2);
    ushort* CL0t = (ushort*)allocB((size_t)256 * 256 * 2);
    ushort* CL1t = (ushort*)allocB((size_t)256 * 256 * 2);
    ushort* CL2t = (ushort*)allocB((size_t)256 * 256 * 2);
    ushort* CWt  = (ushort*)allocB((size_t)1024 * 512 * 2);
    ushort* LWt  = (ushort*)allocB((size_t)1024 * 768 * 2);
    ushort* VW0t = (ushort*)allocB((size_t)512 * 512 * 2);
    ushort* VW1t = (ushort*)allocB((size_t)512 * 512 * 2);
    ushort* vw2  = (ushort*)allocB((size_t)512 * 2);
    ushort* lh_a = (ushort*)allocB((size_t)NL * FM * 2);
    ushort* lh_b = (ushort*)allocB((size_t)NL * FM * 2);
    ushort* ch_a = (ushort*)allocB((size_t)NC * FM * 2);
    ushort* ch_b = (ushort*)allocB((size_t)NC * FM * 2);
    ushort* lcm16 = (ushort*)allocB((size_t)NC * FM * 2);
    ushort* clm16 = (ushort*)allocB((size_t)NL * FM * 2);
    ushort* tL    = (ushort*)allocB((size_t)NL * FM * 2);
    ushort* tC    = (ushort*)allocB((size_t)NC * FM * 2);
    ushort* v0    = (ushort*)allocB((size_t)NV * 512 * 2);

    // ---- setup ----
    hipLaunchKernelGGL(transpose_w6_kernel, dim3(256, 6), dim3(256), 0, stream,
                       LCW0, LCW1, LCW2, CLW0, CLW1, CLW2,
                       LC0t, LC1t, LC2t, CL0t, CL1t, CL2t);
    auto tw = [&](const float* in, ushort* o, int K, int N, int ldo, int koff, int perm) {
        hipLaunchKernelGGL(transpose_w_kernel, dim3((K * N + 255) / 256), dim3(256), 0, stream,
                           in, o, K, N, ldo, koff, perm);
    };
    tw(CWx,  CWt, 256, 1024, 512, 0, 1);
    tw(CWh,  CWt, 256, 1024, 512, 256, 1);
    tw(LWx,  LWt, 512, 1024, 768, 0, 1);
    tw(LWh,  LWt, 256, 1024, 768, 512, 1);
    tw(VW0,  VW0t, 512, 512, 512, 0, 0);
    tw(VW1,  VW1t, 512, 512, 512, 0, 0);
    hipLaunchKernelGGL(f2b_kernel, dim3(2), dim3(256), 0, stream, VW2, vw2, 512);
    hipLaunchKernelGGL(permute_bias_kernel, dim3(4), dim3(256), 0, stream, Cb, Cb_p);
    hipLaunchKernelGGL(permute_bias_kernel, dim3(4), dim3(256), 0, stream, Lb, Lb_p);
    hipLaunchKernelGGL(init_all_kernel, dim3(NC * FM / 256), dim3(256), 0, stream,
                       Li, Ci, lh_a, lc32, ch_a, cc32);
    hipLaunchKernelGGL(fill_hist_kernel, dim3((ROUNDS * NV + 255) / 256), dim3(256), 0, stream,
                       logits_hist, Vb2, loss_arr);
    hipLaunchKernelGGL(zero_kernel, dim3((NL + 255) / 256), dim3(256), 0, stream, (float*)deg, NL);
    hipLaunchKernelGGL(csr_count_kernel, dim3((NE + 255) / 256), dim3(256), 0, stream, lits, deg);
    hipLaunchKernelGGL(csr_scan_kernel, dim3(1), dim3(1024), 0, stream, deg, rowptr, nxt);
    hipLaunchKernelGGL(csr_fill_kernel, dim3((NE + 255) / 256), dim3(256), 0, stream, lits, nxt, ecl);

    ushort *lh_c = lh_a, *lh_n = lh_b, *ch_c = ch_a, *ch_n = ch_b;

    for (int r = 0; r < ROUNDS; ++r) {
        // L -> C message MLP (fused 3 layers, W dbuf)
        hipLaunchKernelGGL(mlp3_kernel, dim3(NL / MLPR), dim3(256), 0, stream,
                           lh_c, LC0t, LCb0, LC1t, LCb1, LC2t, LCb2, tL, NL);
        // gather into clauses
        hipLaunchKernelGGL(gather_lc8_kernel, dim3(NC * 32 / 256), dim3(256), 0, stream,
                           tL, lits, lcm16);
        // fused clause z-GEMM + LSTM
        hipLaunchKernelGGL(gemm_lstm_kernel, dim3(8, (NC + 127) / 128), dim3(256), 0, stream,
                           lcm16, 256, ch_c, 256, (const ushort*)0, 0, 0,
                           CWt, Cb_p, cc32, ch_n, NC);
        // C -> L message MLP (fused 3 layers, W dbuf)
        hipLaunchKernelGGL(mlp3_kernel, dim3(NC / MLPR, 1), dim3(256), 0, stream,
                           ch_n, CL0t, CLb0, CL1t, CLb1, CL2t, CLb2, tC, NC);
        // CSR gather into literals
        hipLaunchKernelGGL(gather_cl8_kernel, dim3(NL * 32 / 256), dim3(256), 0, stream,
                           tC, rowptr, ecl, clm16);
        // fused literal z-GEMM + LSTM (A1 = lh with flip row-mapping)
        hipLaunchKernelGGL(gemm_lstm_kernel, dim3(8, (NL + 127) / 128), dim3(256), 0, stream,
                           clm16, 256, lh_c, 256, lh_c, 256, 1,
                           LWt, Lb_p, lc32, lh_n, NL);
        // vote MLP: layer0 GEMM (dbuf), then fused layer1+GEMV (dbuf)
        hipLaunchKernelGGL(gemm16_n64_kernel, dim3(8, (NV + 127) / 128), dim3(256), 0, stream,
                           lh_n, 256, lh_n + (size_t)NV * FM, 256, VW0t, Vb0, v0, NV, 512, 1);
        hipLaunchKernelGGL(gemm16_vote_kernel, dim3(8, (NV + 127) / 128), dim3(256), 0, stream,
                           v0, VW1t, Vb1, vw2, logits_hist + (size_t)r * NV, NV);
        // swap state buffers
        ushort* tswap;
        tswap = lh_c; lh_c = lh_n; lh_n = tswap;
        tswap = ch_c; ch_c = ch_n; ch_n = tswap;
    }

    hipLaunchKernelGGL(loss_all_kernel, dim3((NC + 255) / 256, ROUNDS), dim3(256), 0, stream,
                       logits_hist, lits, loss_arr);
    hipLaunchKernelGGL(final_out_kernel, dim3((NV + 256) / 256), dim3(256), 0, stream,
                       logits_hist, loss_arr, out);
}

// Round 15
// 5394.619 us; speedup vs baseline: 1.0754x; 1.0754x over previous
//
#include <hip/hip_runtime.h>
#include <hip/hip_bf16.h>

#define NV 4000
#define NL 8000
#define NC 16800
#define NE 50400
#define FM 256
#define ROUNDS 32

typedef short s16x8 __attribute__((ext_vector_type(8)));
typedef __bf16 b16x8 __attribute__((ext_vector_type(8)));
typedef float f32x4 __attribute__((ext_vector_type(4)));
union V8 { s16x8 s; b16x8 b; ushort u[8]; };

using gaddr_t = const void __attribute__((address_space(1)))*;
using laddr_t = void __attribute__((address_space(3)))*;

__device__ __forceinline__ float b2f(ushort u) {
    union { uint i; float f; } v; v.i = ((uint)u) << 16; return v.f;
}
__device__ __forceinline__ ushort f2b(float f) {
    __hip_bfloat16 h = __float2bfloat16(f);
    return *(ushort*)&h;
}

// ---------------- utility ----------------
__global__ void zero_kernel(float* __restrict__ p, int n) {
    int i = blockIdx.x * blockDim.x + threadIdx.x;
    if (i < n) p[i] = 0.0f;
}
__global__ void f2b_kernel(const float* __restrict__ src, ushort* __restrict__ dst, int n) {
    int i = blockIdx.x * blockDim.x + threadIdx.x;
    if (i < n) dst[i] = f2b(src[i]);
}
// six 256x256 W [K,N] fp32 -> [N,256] bf16 transposes in one dispatch
__global__ void transpose_w6_kernel(
    const float* __restrict__ s0, const float* __restrict__ s1, const float* __restrict__ s2,
    const float* __restrict__ s3, const float* __restrict__ s4, const float* __restrict__ s5,
    ushort* __restrict__ d0, ushort* __restrict__ d1, ushort* __restrict__ d2,
    ushort* __restrict__ d3, ushort* __restrict__ d4, ushort* __restrict__ d5)
{
    const float* srcs[6] = {s0, s1, s2, s3, s4, s5};
    ushort* dsts[6] = {d0, d1, d2, d3, d4, d5};
    const float* in = srcs[blockIdx.y];
    ushort* out = dsts[blockIdx.y];
    int idx = blockIdx.x * blockDim.x + threadIdx.x;
    int n = idx >> 8, k = idx & 255;
    out[n * 256 + k] = f2b(in[k * 256 + n]);
}
// W [K,N] fp32 -> out [N', ldo] bf16 at k-offset koff; perm: row = (n&255)*4 + (n>>8)
__global__ void transpose_w_kernel(const float* __restrict__ in, ushort* __restrict__ out,
                                   int K, int N, int ldo, int koff, int perm) {
    int idx = blockIdx.x * blockDim.x + threadIdx.x;
    if (idx >= K * N) return;
    int n = idx / K, k = idx - n * K;
    int row = perm ? ((n & 255) * 4 + (n >> 8)) : n;
    out[(size_t)row * ldo + koff + k] = f2b(in[(size_t)k * N + n]);
}
__global__ void permute_bias_kernel(const float* __restrict__ b, float* __restrict__ bp) {
    int n = blockIdx.x * blockDim.x + threadIdx.x;
    if (n < 1024) bp[(n & 255) * 4 + (n >> 8)] = b[n];
}

// ---------------- combined state init ----------------
__global__ void init_all_kernel(const float* __restrict__ Li, const float* __restrict__ Ci,
                                ushort* __restrict__ lh, float* __restrict__ lc32,
                                ushort* __restrict__ ch, float* __restrict__ cc32) {
    int idx = blockIdx.x * blockDim.x + threadIdx.x;
    if (idx < NL * FM) { lh[idx] = f2b(Li[idx & 255] * (1.0f / 16.0f)); lc32[idx] = 0.0f; }
    if (idx < NC * FM) { ch[idx] = f2b(Ci[idx & 255] * (1.0f / 16.0f)); cc32[idx] = 0.0f; }
}
// pre-fill logits_hist with b2 (vote accumulates atomically on top); zero loss_arr
__global__ void fill_hist_kernel(float* __restrict__ hist, const float* __restrict__ b2,
                                 float* __restrict__ loss_arr) {
    int i = blockIdx.x * blockDim.x + threadIdx.x;
    if (i < ROUNDS * NV) hist[i] = b2[0];
    if (i < ROUNDS) loss_arr[i] = 0.0f;
}

// ---------------- CSR build ----------------
__global__ void csr_count_kernel(const int* __restrict__ lits, int* __restrict__ deg) {
    int e = blockIdx.x * blockDim.x + threadIdx.x;
    if (e >= NE) return;
    int l = lits[e];
    int v = (l > 0 ? l : -l) - 1;
    int li = (l > 0) ? v : NV + v;
    atomicAdd(&deg[li], 1);
}
// parallel scan: 1024 threads x 8 elems, Hillis-Steele block scan
__global__ __launch_bounds__(1024) void csr_scan_kernel(const int* __restrict__ deg,
                                                        int* __restrict__ rowptr,
                                                        int* __restrict__ nxt) {
    __shared__ int ls[1024];
    int t = threadIdx.x;
    int base = t * 8;
    int local[8];
    int s = 0;
    #pragma unroll
    for (int i = 0; i < 8; ++i) {
        int idx = base + i;
        int d = (idx < NL) ? deg[idx] : 0;
        local[i] = s;
        s += d;
    }
    ls[t] = s;
    __syncthreads();
    for (int st = 1; st < 1024; st <<= 1) {
        int v = (t >= st) ? ls[t - st] : 0;
        __syncthreads();
        ls[t] += v;
        __syncthreads();
    }
    int prefix = (t == 0) ? 0 : ls[t - 1];
    #pragma unroll
    for (int i = 0; i < 8; ++i) {
        int idx = base + i;
        if (idx < NL) { int v = prefix + local[i]; rowptr[idx] = v; nxt[idx] = v; }
    }
    if (t == 1023) rowptr[NL] = ls[1023];
}
__global__ void csr_fill_kernel(const int* __restrict__ lits, int* __restrict__ nxt,
                                int* __restrict__ ecl) {
    int e = blockIdx.x * blockDim.x + threadIdx.x;
    if (e >= NE) return;
    int l = lits[e];
    int v = (l > 0 ? l : -l) - 1;
    int li = (l > 0) ? v : NV + v;
    int pos = atomicAdd(&nxt[li], 1);
    ecl[pos] = e / 3;
}

#define BKT 64

// =========== Fused 3-layer MLP (256->256->256->256), relu/relu/linear ===========
#define MLPR 32
__global__ __launch_bounds__(256) void mlp3_kernel(
    const ushort* __restrict__ A,
    const ushort* __restrict__ W0t, const float* __restrict__ b0,
    const ushort* __restrict__ W1t, const float* __restrict__ b1,
    const ushort* __restrict__ W2t, const float* __restrict__ b2,
    ushort* __restrict__ out, int M)
{
    __shared__ __align__(16) ushort As[MLPR * BKT];
    __shared__ __align__(16) ushort Wl[256 * BKT];
    __shared__ __align__(16) ushort Ab[MLPR * 264];
    const int tid = threadIdx.x;
    const int lane = tid & 63, wid = tid >> 6;
    const int rowBase = blockIdx.x * MLPR;
    const int lr = lane >> 3, ql = (lane & 7) ^ lr;
    const int cl16 = lane & 15, kg = lane >> 4;

    const ushort* Wt[3] = {W0t, W1t, W2t};
    const float*  bs[3] = {b0, b1, b2};

    #pragma unroll
    for (int layer = 0; layer < 3; ++layer) {
        f32x4 acc[2][4];
        #pragma unroll
        for (int i = 0; i < 2; ++i)
            #pragma unroll
            for (int j = 0; j < 4; ++j) acc[i][j] = (f32x4){0.f, 0.f, 0.f, 0.f};

        for (int kt = 0; kt < 4; ++kt) {
            __syncthreads();
            #pragma unroll
            for (int t = 0; t < 8; ++t) {
                int row = wid * 64 + t * 8 + lr;
                __builtin_amdgcn_global_load_lds(
                    (gaddr_t)(Wt[layer] + (size_t)row * 256 + kt * 64 + ql * 8),
                    (laddr_t)&Wl[(wid * 64 + t * 8) * BKT + lane * 8], 16, 0, 0);
            }
            if (layer == 0) {
                int row = rowBase + wid * 8 + lr;
                if (row > M - 1) row = M - 1;
                __builtin_amdgcn_global_load_lds(
                    (gaddr_t)(A + (size_t)row * 256 + kt * 64 + ql * 8),
                    (laddr_t)&As[wid * 512 + lane * 8], 16, 0, 0);
            }
            __syncthreads();
            #pragma unroll
            for (int s = 0; s < 2; ++s) {
                int kq8 = s * 4 + kg;
                V8 af[2], bf[4];
                #pragma unroll
                for (int i = 0; i < 2; ++i) {
                    int m = i * 16 + cl16;
                    if (layer == 0)
                        af[i].s = *(const s16x8*)&As[m * BKT + ((kq8 ^ (m & 7)) * 8)];
                    else
                        af[i].s = *(const s16x8*)&Ab[m * 264 + kt * 64 + kq8 * 8];
                }
                #pragma unroll
                for (int j = 0; j < 4; ++j) {
                    int n = wid * 64 + j * 16 + cl16;
                    bf[j].s = *(const s16x8*)&Wl[n * BKT + ((kq8 ^ (n & 7)) * 8)];
                }
                #pragma unroll
                for (int i = 0; i < 2; ++i)
                    #pragma unroll
                    for (int j = 0; j < 4; ++j)
                        acc[i][j] = __builtin_amdgcn_mfma_f32_16x16x32_bf16(
                            af[i].b, bf[j].b, acc[i][j], 0, 0, 0);
            }
        }
        __syncthreads();
        const int rq = (lane >> 4) * 4;
        #pragma unroll
        for (int i = 0; i < 2; ++i)
            #pragma unroll
            for (int r = 0; r < 4; ++r) {
                int row = i * 16 + rq + r;
                #pragma unroll
                for (int j = 0; j < 4; ++j) {
                    int col = wid * 64 + j * 16 + cl16;
                    float v = acc[i][j][r] + bs[layer][col];
                    if (layer < 2) {
                        Ab[row * 264 + col] = f2b(fmaxf(v, 0.0f));
                    } else {
                        int grow = rowBase + row;
                        if (grow < M) out[(size_t)grow * 256 + col] = f2b(v);
                    }
                }
            }
    }
}

// =========== MFMA bf16 GEMM 128x64 tile ===========
__global__ __launch_bounds__(256) void gemm16_n64_kernel(
    const ushort* __restrict__ A0, int K0,
    const ushort* __restrict__ A1, int K1,
    const ushort* __restrict__ Bt, const float* __restrict__ bias,
    ushort* __restrict__ C, int M, int N, int relu)
{
    __shared__ __align__(16) ushort Al[128 * BKT];
    __shared__ __align__(16) ushort Bl[64 * BKT];
    const int Ktot = K0 + K1;
    const int tid = threadIdx.x;
    const int rowBase = blockIdx.y * 128, colBase = blockIdx.x * 64;
    const int lane = tid & 63, wid = tid >> 6;
    const int wm = (wid & 1) * 64, wn = (wid >> 1) * 32;
    const int lr = lane >> 3, ql = (lane & 7) ^ lr;

    f32x4 acc[4][2];
    #pragma unroll
    for (int i = 0; i < 4; ++i)
        #pragma unroll
        for (int j = 0; j < 2; ++j) acc[i][j] = (f32x4){0.f, 0.f, 0.f, 0.f};

    for (int k0 = 0; k0 < Ktot; k0 += BKT) {
        const ushort* As; int ks, lda;
        if (k0 < K0) { As = A0; ks = k0; lda = K0; }
        else         { As = A1; ks = k0 - K0; lda = K1; }
        __syncthreads();
        #pragma unroll
        for (int t = 0; t < 4; ++t) {
            int rloc = (wid * 4 + t) * 8 + lr;
            int ga = rowBase + rloc; if (ga > M - 1) ga = M - 1;
            __builtin_amdgcn_global_load_lds((gaddr_t)(As + (size_t)ga * lda + ks + ql * 8),
                                             (laddr_t)&Al[(wid * 4 + t) * 512], 16, 0, 0);
        }
        #pragma unroll
        for (int t = 0; t < 2; ++t) {
            int rloc = (wid * 2 + t) * 8 + lr;
            __builtin_amdgcn_global_load_lds((gaddr_t)(Bt + (size_t)(colBase + rloc) * Ktot + k0 + ql * 8),
                                             (laddr_t)&Bl[(wid * 2 + t) * 512], 16, 0, 0);
        }
        __syncthreads();
        const int cl = lane & 15, kg = lane >> 4;
        #pragma unroll
        for (int s = 0; s < 2; ++s) {
            V8 af[4], bf[2];
            #pragma unroll
            for (int i = 0; i < 4; ++i) {
                int m = wm + i * 16 + cl;
                af[i].s = *(const s16x8*)&Al[m * BKT + (((s * 4 + kg) ^ (m & 7)) * 8)];
            }
            #pragma unroll
            for (int j = 0; j < 2; ++j) {
                int n = wn + j * 16 + cl;
                bf[j].s = *(const s16x8*)&Bl[n * BKT + (((s * 4 + kg) ^ (n & 7)) * 8)];
            }
            #pragma unroll
            for (int i = 0; i < 4; ++i)
                #pragma unroll
                for (int j = 0; j < 2; ++j)
                    acc[i][j] = __builtin_amdgcn_mfma_f32_16x16x32_bf16(af[i].b, bf[j].b,
                                                                        acc[i][j], 0, 0, 0);
        }
    }
    const int rq = (lane >> 4) * 4, cl = lane & 15;
    #pragma unroll
    for (int i = 0; i < 4; ++i)
        #pragma unroll
        for (int r = 0; r < 4; ++r) {
            int grow = rowBase + wm + i * 16 + rq + r;
            if (grow >= M) continue;
            #pragma unroll
            for (int j = 0; j < 2; ++j) {
                int gcol = colBase + wn + j * 16 + cl;
                float v = acc[i][j][r] + bias[gcol];
                if (relu) v = fmaxf(v, 0.0f);
                C[(size_t)grow * N + gcol] = f2b(v);
            }
        }
}

// =========== vote layer-1 GEMM + GEMV fused: logits[row] += dot(relu(v0@W1+b1), w2) ==
__global__ __launch_bounds__(256) void gemm16_vote_kernel(
    const ushort* __restrict__ A0,              // v0 [M,512]
    const ushort* __restrict__ Bt,              // VW1t [512,512]
    const float* __restrict__ bias,             // Vb1
    const ushort* __restrict__ w2,              // vw2 bf16 [512]
    float* __restrict__ logits, int M)          // pre-filled with b2
{
    __shared__ __align__(16) ushort Al[128 * BKT];
    __shared__ __align__(16) ushort Bl[64 * BKT];
    const int Ktot = 512;
    const int tid = threadIdx.x;
    const int rowBase = blockIdx.y * 128, colBase = blockIdx.x * 64;
    const int lane = tid & 63, wid = tid >> 6;
    const int wm = (wid & 1) * 64, wn = (wid >> 1) * 32;
    const int lr = lane >> 3, ql = (lane & 7) ^ lr;

    f32x4 acc[4][2];
    #pragma unroll
    for (int i = 0; i < 4; ++i)
        #pragma unroll
        for (int j = 0; j < 2; ++j) acc[i][j] = (f32x4){0.f, 0.f, 0.f, 0.f};

    for (int k0 = 0; k0 < Ktot; k0 += BKT) {
        __syncthreads();
        #pragma unroll
        for (int t = 0; t < 4; ++t) {
            int rloc = (wid * 4 + t) * 8 + lr;
            int ga = rowBase + rloc; if (ga > M - 1) ga = M - 1;
            __builtin_amdgcn_global_load_lds((gaddr_t)(A0 + (size_t)ga * Ktot + k0 + ql * 8),
                                             (laddr_t)&Al[(wid * 4 + t) * 512], 16, 0, 0);
        }
        #pragma unroll
        for (int t = 0; t < 2; ++t) {
            int rloc = (wid * 2 + t) * 8 + lr;
            __builtin_amdgcn_global_load_lds((gaddr_t)(Bt + (size_t)(colBase + rloc) * Ktot + k0 + ql * 8),
                                             (laddr_t)&Bl[(wid * 2 + t) * 512], 16, 0, 0);
        }
        __syncthreads();
        const int cl = lane & 15, kg = lane >> 4;
        #pragma unroll
        for (int s = 0; s < 2; ++s) {
            V8 af[4], bf[2];
            #pragma unroll
            for (int i = 0; i < 4; ++i) {
                int m = wm + i * 16 + cl;
                af[i].s = *(const s16x8*)&Al[m * BKT + (((s * 4 + kg) ^ (m & 7)) * 8)];
            }
            #pragma unroll
            for (int j = 0; j < 2; ++j) {
                int n = wn + j * 16 + cl;
                bf[j].s = *(const s16x8*)&Bl[n * BKT + (((s * 4 + kg) ^ (n & 7)) * 8)];
            }
            #pragma unroll
            for (int i = 0; i < 4; ++i)
                #pragma unroll
                for (int j = 0; j < 2; ++j)
                    acc[i][j] = __builtin_amdgcn_mfma_f32_16x16x32_bf16(af[i].b, bf[j].b,
                                                                        acc[i][j], 0, 0, 0);
        }
    }
    // epilogue: dot relu(acc+b1) with w2, reduce over 16 col-lanes, atomic per row
    const int rq = (lane >> 4) * 4, cl = lane & 15;
    #pragma unroll
    for (int i = 0; i < 4; ++i)
        #pragma unroll
        for (int r = 0; r < 4; ++r) {
            int grow = rowBase + wm + i * 16 + rq + r;
            float s = 0.0f;
            #pragma unroll
            for (int j = 0; j < 2; ++j) {
                int gcol = colBase + wn + j * 16 + cl;
                float h1 = b2f(f2b(fmaxf(acc[i][j][r] + bias[gcol], 0.0f)));
                s += h1 * b2f(w2[gcol]);
            }
            s += __shfl_xor(s, 1);
            s += __shfl_xor(s, 2);
            s += __shfl_xor(s, 4);
            s += __shfl_xor(s, 8);
            if (cl == 0 && grow < M) atomicAdd(&logits[grow], s);
        }
}

// =========== Fused z-GEMM + LSTM (N=1024, gate-interleaved weights) ===========
__global__ __launch_bounds__(256) void gemm_lstm_kernel(
    const ushort* __restrict__ A0, int K0,
    const ushort* __restrict__ A1, int K1,
    const ushort* __restrict__ A2, int K2,
    int flip1,
    const ushort* __restrict__ Bt, const float* __restrict__ biasP,
    float* __restrict__ c32, ushort* __restrict__ h_out, int M)
{
    __shared__ __align__(16) ushort smem[2 * 128 * BKT];
    ushort* Al = smem;
    ushort* Bl = smem + 128 * BKT;
    const int Ktot = K0 + K1 + K2;
    const int tid = threadIdx.x;
    const int rowBase = blockIdx.y * 128, colBase = blockIdx.x * 128;
    const int lane = tid & 63, wid = tid >> 6;
    const int wm = (wid >> 1) * 64, wn = (wid & 1) * 64;
    const int lr = lane >> 3, ql = (lane & 7) ^ lr;

    f32x4 acc[4][4];
    #pragma unroll
    for (int i = 0; i < 4; ++i)
        #pragma unroll
        for (int j = 0; j < 4; ++j) acc[i][j] = (f32x4){0.f, 0.f, 0.f, 0.f};

    for (int k0 = 0; k0 < Ktot; k0 += BKT) {
        const ushort* As; int ks, lda, flip;
        if (k0 < K0)           { As = A0; ks = k0;           lda = K0; flip = 0; }
        else if (k0 < K0 + K1) { As = A1; ks = k0 - K0;      lda = K1; flip = flip1; }
        else                   { As = A2; ks = k0 - K0 - K1; lda = K2; flip = 0; }
        __syncthreads();
        #pragma unroll
        for (int t = 0; t < 4; ++t) {
            int rloc = (wid * 4 + t) * 8 + lr;
            int ga = rowBase + rloc; if (ga > M - 1) ga = M - 1;
            if (flip) ga = (ga < NV) ? ga + NV : ga - NV;
            __builtin_amdgcn_global_load_lds((gaddr_t)(As + (size_t)ga * lda + ks + ql * 8),
                                             (laddr_t)&Al[(wid * 4 + t) * 512], 16, 0, 0);
            __builtin_amdgcn_global_load_lds((gaddr_t)(Bt + (size_t)(colBase + rloc) * Ktot + k0 + ql * 8),
                                             (laddr_t)&Bl[(wid * 4 + t) * 512], 16, 0, 0);
        }
        __syncthreads();
        const int cl = lane & 15, kg = lane >> 4;
        #pragma unroll
        for (int s = 0; s < 2; ++s) {
            V8 af[4], bf[4];
            #pragma unroll
            for (int i = 0; i < 4; ++i) {
                int m = wm + i * 16 + cl;
                af[i].s = *(const s16x8*)&Al[m * BKT + (((s * 4 + kg) ^ (m & 7)) * 8)];
            }
            #pragma unroll
            for (int j = 0; j < 4; ++j) {
                int n = wn + j * 16 + cl;
                bf[j].s = *(const s16x8*)&Bl[n * BKT + (((s * 4 + kg) ^ (n & 7)) * 8)];
            }
            #pragma unroll
            for (int i = 0; i < 4; ++i)
                #pragma unroll
                for (int j = 0; j < 4; ++j)
                    acc[i][j] = __builtin_amdgcn_mfma_f32_16x16x32_bf16(af[i].b, bf[j].b,
                                                                        acc[i][j], 0, 0, 0);
        }
    }
    __syncthreads();
    {
        const int rq = (lane >> 4) * 4, cl = lane & 15;
        #pragma unroll
        for (int i = 0; i < 4; ++i)
            #pragma unroll
            for (int r = 0; r < 4; ++r) {
                int rl = wm + i * 16 + rq + r;
                #pragma unroll
                for (int j = 0; j < 4; ++j) {
                    int clc = wn + j * 16 + cl;
                    smem[rl * 128 + clc] = f2b(acc[i][j][r] + biasP[colBase + clc]);
                }
            }
    }
    __syncthreads();
    const int fl = tid & 31, rg = tid >> 5;
    const int fglob = (colBase >> 2) + fl;
    #pragma unroll
    for (int k = 0; k < 16; ++k) {
        int rl = rg + 8 * k;
        int grow = rowBase + rl;
        if (grow >= M) continue;
        ushort4 g4 = *(const ushort4*)&smem[rl * 128 + fl * 4];
        float zi = b2f(g4.x), zf = b2f(g4.y), zg = b2f(g4.z), zo = b2f(g4.w);
        size_t ci = (size_t)grow * FM + fglob;
        float cold = c32[ci];
        float si = 1.0f / (1.0f + __expf(-zi));
        float sf = 1.0f / (1.0f + __expf(-zf));
        float so = 1.0f / (1.0f + __expf(-zo));
        float cn = sf * cold + si * tanhf(zg);
        float hn = so * tanhf(cn);
        c32[ci] = cn;
        h_out[ci] = f2b(hn);
    }
}

// ---------------- gather (vectorized x8) ----------------
__global__ void gather_lc8_kernel(const ushort* __restrict__ pre, const int* __restrict__ lits,
                                  ushort* __restrict__ out) {
    int idx = blockIdx.x * blockDim.x + threadIdx.x;
    if (idx >= NC * 32) return;
    int c = idx >> 5, f8 = (idx & 31) * 8;
    const int* cl = lits + c * 3;
    float s[8] = {};
    #pragma unroll
    for (int k = 0; k < 3; ++k) {
        int l = cl[k];
        int v = (l > 0 ? l : -l) - 1;
        int li = (l > 0) ? v : NV + v;
        V8 x; x.s = *(const s16x8*)&pre[(size_t)li * FM + f8];
        #pragma unroll
        for (int e = 0; e < 8; ++e) s[e] += b2f(x.u[e]);
    }
    V8 o;
    #pragma unroll
    for (int e = 0; e < 8; ++e) o.u[e] = f2b(s[e]);
    *(s16x8*)&out[(size_t)c * FM + f8] = o.s;
}

__global__ void gather_cl8_kernel(const ushort* __restrict__ pre, const int* __restrict__ rowptr,
                                  const int* __restrict__ ecl, ushort* __restrict__ out) {
    int idx = blockIdx.x * blockDim.x + threadIdx.x;
    if (idx >= NL * 32) return;
    int li = idx >> 5, f8 = (idx & 31) * 8;
    int j0 = rowptr[li], j1 = rowptr[li + 1];
    float s[8] = {};
    for (int j = j0; j < j1; ++j) {
        V8 x; x.s = *(const s16x8*)&pre[(size_t)ecl[j] * FM + f8];
        #pragma unroll
        for (int e = 0; e < 8; ++e) s[e] += b2f(x.u[e]);
    }
    V8 o;
    #pragma unroll
    for (int e = 0; e < 8; ++e) o.u[e] = f2b(s[e]);
    *(s16x8*)&out[(size_t)li * FM + f8] = o.s;
}

// ---------------- batched clause loss over all rounds ----------------
__global__ __launch_bounds__(256) void loss_all_kernel(
    const float* __restrict__ logits_hist, const int* __restrict__ lits,
    float* __restrict__ loss_arr)
{
    __shared__ float sm[256];
    const int r = blockIdx.y;
    const float* logits = logits_hist + (size_t)r * NV;
    int c = blockIdx.x * 256 + threadIdx.x;
    float t2 = 0.0f;
    if (c < NC) {
        const int* cl = lits + c * 3;
        float s = 0.0f;
        #pragma unroll
        for (int k = 0; k < 3; ++k) {
            int l = cl[k];
            int v = (l > 0 ? l : -l) - 1;
            float sg = (l > 0) ? 1.0f : -1.0f;
            float val = logits[v] * sg;
            s += fmaxf(val, 0.0f) + log1pf(__expf(-fabsf(val)));
        }
        float cv = __expf(-s);
        float t = -logf(1.0f - cv + 1e-8f);
        t2 = t * t;
    }
    sm[threadIdx.x] = t2;
    __syncthreads();
    for (int st = 128; st > 0; st >>= 1) {
        if (threadIdx.x < st) sm[threadIdx.x] += sm[threadIdx.x + st];
        __syncthreads();
    }
    if (threadIdx.x == 0) atomicAdd(&loss_arr[r], sm[0]);
}

// ---------------- final: copy last-round logits + mean loss ----------------
__global__ void final_out_kernel(const float* __restrict__ logits_hist,
                                 const float* __restrict__ loss_arr,
                                 float* __restrict__ out) {
    int i = blockIdx.x * blockDim.x + threadIdx.x;
    if (i < NV) out[i] = logits_hist[(size_t)(ROUNDS - 1) * NV + i];
    if (i == NV) {
        float s = 0.0f;
        for (int r = 0; r < ROUNDS; ++r) s += loss_arr[r];
        out[NV] = s * (1.0f / (float)ROUNDS);
    }
}

extern "C" void kernel_launch(void* const* d_in, const int* in_sizes, int n_in,
                              void* d_out, int out_size, void* d_ws, size_t ws_size,
                              hipStream_t stream) {
    const int* lits = (const int*)d_in[0];
    float* out = (float*)d_out;

    const float* Li   = (const float*)d_in[2];
    const float* Ci   = (const float*)d_in[3];
    const float* LCW0 = (const float*)d_in[4];
    const float* LCb0 = (const float*)d_in[5];
    const float* LCW1 = (const float*)d_in[6];
    const float* LCb1 = (const float*)d_in[7];
    const float* LCW2 = (const float*)d_in[8];
    const float* LCb2 = (const float*)d_in[9];
    const float* CLW0 = (const float*)d_in[10];
    const float* CLb0 = (const float*)d_in[11];
    const float* CLW1 = (const float*)d_in[12];
    const float* CLb1 = (const float*)d_in[13];
    const float* CLW2 = (const float*)d_in[14];
    const float* CLb2 = (const float*)d_in[15];
    const float* CWx  = (const float*)d_in[16];
    const float* CWh  = (const float*)d_in[17];
    const float* Cb   = (const float*)d_in[18];
    const float* LWx  = (const float*)d_in[19];
    const float* LWh  = (const float*)d_in[20];
    const float* Lb   = (const float*)d_in[21];
    const float* VW0  = (const float*)d_in[22];
    const float* Vb0  = (const float*)d_in[23];
    const float* VW1  = (const float*)d_in[24];
    const float* Vb1  = (const float*)d_in[25];
    const float* VW2  = (const float*)d_in[26];
    const float* Vb2  = (const float*)d_in[27];
    (void)in_sizes; (void)n_in; (void)out_size; (void)ws_size;

    // ---- ws layout ----
    char* base = (char*)d_ws;
    size_t off = 0;
    auto allocB = [&](size_t bytes) {
        void* p = base + off;
        off += (bytes + 15) & ~(size_t)15;
        return p;
    };
    float*  loss_arr    = (float*)allocB(ROUNDS * 4);
    float*  logits_hist = (float*)allocB((size_t)ROUNDS * NV * 4);
    float*  lc32        = (float*)allocB((size_t)NL * FM * 4);
    float*  cc32        = (float*)allocB((size_t)NC * FM * 4);
    float*  Cb_p        = (float*)allocB(1024 * 4);
    float*  Lb_p        = (float*)allocB(1024 * 4);
    int*    deg         = (int*)allocB(NL * 4);
    int*    rowptr      = (int*)allocB((NL + 1) * 4);
    int*    nxt         = (int*)allocB(NL * 4);
    int*    ecl         = (int*)allocB(NE * 4);
    ushort* LC0t = (ushort*)allocB((size_t)256 * 256 * 2);
    ushort* LC1t = (ushort*)allocB((size_t)256 * 256 * 2);
    ushort* LC2t = (ushort*)allocB((size_t)256 * 256 * 2);
    ushort* CL0t = (ushort*)allocB((size_t)256 * 256 * 2);
    ushort* CL1t = (ushort*)allocB((size_t)256 * 256 * 2);
    ushort* CL2t = (ushort*)allocB((size_t)256 * 256 * 2);
    ushort* CWt  = (ushort*)allocB((size_t)1024 * 512 * 2);
    ushort* LWt  = (ushort*)allocB((size_t)1024 * 768 * 2);
    ushort* VW0t = (ushort*)allocB((size_t)512 * 512 * 2);
    ushort* VW1t = (ushort*)allocB((size_t)512 * 512 * 2);
    ushort* vw2  = (ushort*)allocB((size_t)512 * 2);
    ushort* lh_a = (ushort*)allocB((size_t)NL * FM * 2);
    ushort* lh_b = (ushort*)allocB((size_t)NL * FM * 2);
    ushort* ch_a = (ushort*)allocB((size_t)NC * FM * 2);
    ushort* ch_b = (ushort*)allocB((size_t)NC * FM * 2);
    ushort* lcm16 = (ushort*)allocB((size_t)NC * FM * 2);
    ushort* clm16 = (ushort*)allocB((size_t)NL * FM * 2);
    ushort* tL    = (ushort*)allocB((size_t)NL * FM * 2);
    ushort* tC    = (ushort*)allocB((size_t)NC * FM * 2);
    ushort* v0    = (ushort*)allocB((size_t)NV * 512 * 2);

    // ---- setup ----
    hipLaunchKernelGGL(transpose_w6_kernel, dim3(256, 6), dim3(256), 0, stream,
                       LCW0, LCW1, LCW2, CLW0, CLW1, CLW2,
                       LC0t, LC1t, LC2t, CL0t, CL1t, CL2t);
    auto tw = [&](const float* in, ushort* o, int K, int N, int ldo, int koff, int perm) {
        hipLaunchKernelGGL(transpose_w_kernel, dim3((K * N + 255) / 256), dim3(256), 0, stream,
                           in, o, K, N, ldo, koff, perm);
    };
    tw(CWx,  CWt, 256, 1024, 512, 0, 1);
    tw(CWh,  CWt, 256, 1024, 512, 256, 1);
    tw(LWx,  LWt, 512, 1024, 768, 0, 1);
    tw(LWh,  LWt, 256, 1024, 768, 512, 1);
    tw(VW0,  VW0t, 512, 512, 512, 0, 0);
    tw(VW1,  VW1t, 512, 512, 512, 0, 0);
    hipLaunchKernelGGL(f2b_kernel, dim3(2), dim3(256), 0, stream, VW2, vw2, 512);
    hipLaunchKernelGGL(permute_bias_kernel, dim3(4), dim3(256), 0, stream, Cb, Cb_p);
    hipLaunchKernelGGL(permute_bias_kernel, dim3(4), dim3(256), 0, stream, Lb, Lb_p);
    hipLaunchKernelGGL(init_all_kernel, dim3(NC * FM / 256), dim3(256), 0, stream,
                       Li, Ci, lh_a, lc32, ch_a, cc32);
    hipLaunchKernelGGL(fill_hist_kernel, dim3((ROUNDS * NV + 255) / 256), dim3(256), 0, stream,
                       logits_hist, Vb2, loss_arr);
    hipLaunchKernelGGL(zero_kernel, dim3((NL + 255) / 256), dim3(256), 0, stream, (float*)deg, NL);
    hipLaunchKernelGGL(csr_count_kernel, dim3((NE + 255) / 256), dim3(256), 0, stream, lits, deg);
    hipLaunchKernelGGL(csr_scan_kernel, dim3(1), dim3(1024), 0, stream, deg, rowptr, nxt);
    hipLaunchKernelGGL(csr_fill_kernel, dim3((NE + 255) / 256), dim3(256), 0, stream, lits, nxt, ecl);

    ushort *lh_c = lh_a, *lh_n = lh_b, *ch_c = ch_a, *ch_n = ch_b;

    for (int r = 0; r < ROUNDS; ++r) {
        // L -> C message MLP (fused 3 layers)
        hipLaunchKernelGGL(mlp3_kernel, dim3(NL / MLPR), dim3(256), 0, stream,
                           lh_c, LC0t, LCb0, LC1t, LCb1, LC2t, LCb2, tL, NL);
        // gather into clauses
        hipLaunchKernelGGL(gather_lc8_kernel, dim3(NC * 32 / 256), dim3(256), 0, stream,
                           tL, lits, lcm16);
        // fused clause z-GEMM + LSTM
        hipLaunchKernelGGL(gemm_lstm_kernel, dim3(8, (NC + 127) / 128), dim3(256), 0, stream,
                           lcm16, 256, ch_c, 256, (const ushort*)0, 0, 0,
                           CWt, Cb_p, cc32, ch_n, NC);
        // C -> L message MLP (fused 3 layers)
        hipLaunchKernelGGL(mlp3_kernel, dim3(NC / MLPR, 1), dim3(256), 0, stream,
                           ch_n, CL0t, CLb0, CL1t, CLb1, CL2t, CLb2, tC, NC);
        // CSR gather into literals
        hipLaunchKernelGGL(gather_cl8_kernel, dim3(NL * 32 / 256), dim3(256), 0, stream,
                           tC, rowptr, ecl, clm16);
        // fused literal z-GEMM + LSTM (A1 = lh with flip row-mapping)
        hipLaunchKernelGGL(gemm_lstm_kernel, dim3(8, (NL + 127) / 128), dim3(256), 0, stream,
                           clm16, 256, lh_c, 256, lh_c, 256, 1,
                           LWt, Lb_p, lc32, lh_n, NL);
        // vote MLP: layer0 GEMM, then fused layer1+GEMV into pre-biased logits slot
        hipLaunchKernelGGL(gemm16_n64_kernel, dim3(8, (NV + 127) / 128), dim3(256), 0, stream,
                           lh_n, 256, lh_n + (size_t)NV * FM, 256, VW0t, Vb0, v0, NV, 512, 1);
        hipLaunchKernelGGL(gemm16_vote_kernel, dim3(8, (NV + 127) / 128), dim3(256), 0, stream,
                           v0, VW1t, Vb1, vw2, logits_hist + (size_t)r * NV, NV);
        // swap state buffers
        ushort* tswap;
        tswap = lh_c; lh_c = lh_n; lh_n = tswap;
        tswap = ch_c; ch_c = ch_n; ch_n = tswap;
    }

    hipLaunchKernelGGL(loss_all_kernel, dim3((NC + 255) / 256, ROUNDS), dim3(256), 0, stream,
                       logits_hist, lits, loss_arr);
    hipLaunchKernelGGL(final_out_kernel, dim3((NV + 256) / 256), dim3(256), 0, stream,
                       logits_hist, loss_arr, out);
}